// Round 9
// baseline (150.589 us; speedup 1.0000x reference)
//
#include <hip/hip_runtime.h>

namespace {
constexpr float kLrelu = 0.2f;
constexpr float kEps   = 1e-5f;
}

typedef short bf16x8 __attribute__((ext_vector_type(8)));
typedef float f32x4  __attribute__((ext_vector_type(4)));

// LDS-only barrier: waits local ops, does NOT drain vmcnt -> global prefetch
// loads stay in flight across the barrier.
#define LDS_BARRIER() asm volatile("s_waitcnt lgkmcnt(0)\n\ts_barrier" ::: "memory")

// round-to-nearest-even f32 -> bf16 (inputs are finite)
static __device__ __forceinline__ unsigned f2bf(float x) {
  unsigned u = __float_as_uint(x);
  return (u + 0x7FFFu + ((u >> 16) & 1u)) >> 16;
}
static __device__ __forceinline__ unsigned packbf(float a, float b) {
  return f2bf(a) | (f2bf(b) << 16);
}

// Grouped conv as 64 x [256x512x2048] bf16-MFMA GEMM + per-channel stats.
// Block = (g, z-tile 64, m-tile 256), 512 threads = 8 waves, INTRA-BLOCK
// K-SPLIT: waves 0-3 (kt=0) do K-chunks 0..31, waves 4-7 (kt=1) do 32..63 in
// PRIVATE LDS regions -> 4 independent dependency chains per SIMD (R5-R8 were
// latency-bound at 2 waves/SIMD with lockstep blocks). K-split duplicates no
// staging and no global traffic. Epilogue: kt1 dumps acc to LDS, kt0 adds,
// then stats + fold store as before.
// Writes raw conv output into d_out in FOLD layout: out[b][z][hp*4+oy][wp*4+ox].
__global__ __launch_bounds__(512, 4) void conv_mfma(
    const float* __restrict__ input,   // [32,128,64,64]
    const float* __restrict__ weight,  // [16384, 2048]  (k = nc*16 + ky*4 + kx)
    float* __restrict__ out,           // [32,256,32,32]
    float* __restrict__ stats)         // [16384][2] (sum, sumsq)
{
  // LDS carve (72 KB): per kt: raw dbuf 2x8KB, Bs 16KB, As 4KB.
  //   [0,32768):      raw[kt][buf]   at kt*16384 + buf*8192 (floats)
  //   [32768,65536):  Bs[kt]         at 32768 + kt*16384
  //   [65536,73728):  As[kt]         at 65536 + kt*4096
  // Epilogue reuses [0,65536) as the 64KB combine scratch.
  __shared__ __align__(16) char lds[73728];

  const int bid  = blockIdx.x;
  const int orig = (bid & 7) * 64 + (bid >> 3);   // XCD-chunked (512 % 8 == 0)
  const int g    = orig >> 3;
  const int zt   = (orig >> 1) & 3;
  const int mt   = orig & 1;
  const int hp = g >> 3, wp = g & 7;
  const int z0 = zt * 64;
  const int m0 = mt * 256;

  const int tid  = threadIdx.x;
  const int lane = tid & 63;
  const int kt   = tid >> 8;                      // K-half 0/1
  const int tl   = tid & 255;                     // thread-in-half
  const int wl   = (tid >> 6) & 3;                // wave-in-half, m = m0 + wl*64
  const int llo  = lane & 15, lhi = lane >> 4;

  float* const rawB0 = (float*)(lds + kt * 16384);           // buf0
  float* const rawB1 = rawB0 + 2048;                         // buf1 (+8KB)
  char*  const BsB   = lds + 32768 + kt * 16384;
  char*  const AsB   = lds + 65536 + kt * 4096;

  // -------- raw staging: thread -> patch pl=tl>>3, f4=tl&7 (rows 0-3 / 4-7)
  const int pl_s = tl >> 3;
  const int f4   = tl & 7;
  const int bl_s = pl_s >> 1;
  const int ncs_s = pl_s & 1;
  const int py_s = f4 >> 1, h_s = f4 & 1;
  const float* const gsrc = input
      + ((size_t)(mt * 16 + bl_s) * 128 + ncs_s) * 4096
      + (size_t)kt * 262144                           // kt*64 nc
      + (hp * 8 + py_s) * 64 + wp * 8 + (h_s << 2);   // + ck*8192 per chunk
  const int roffA = pl_s * 64 + ((py_s ^ (bl_s & 7)) << 3) + (h_s << 2);
  const int roffB = pl_s * 64 + (((py_s + 4) ^ (bl_s & 7)) << 3) + (h_s << 2);
  float* const rd0a = rawB0 + roffA;  float* const rd0b = rawB0 + roffB;
  float* const rd1a = rawB1 + roffA;  float* const rd1b = rawB1 + roffB;

  // -------- weight staging: rows az0=tl>>3 and az0+32; kq=tl&7 (k=kq*4..+3)
  const int az0 = tl >> 3;
  const int kq  = tl & 7;
  const float* const wsrc =
      weight + ((size_t)(g * 256 + z0 + az0)) * 2048 + kt * 1024 + kq * 4;
  const int aswz = (az0 >> 1) & 3;   // ((az0+32)>>1)&3 is identical
  char* const ad0 = AsB + az0 * 64 + (((kq >> 1) ^ aswz) << 4) + ((kq & 1) << 3);
  char* const ad1 = ad0 + 32 * 64;

  // -------- row-gather: thread -> (bl=tl>>4, oy=(tl>>2)&3, ky=tl&3)
  const int bl_g = tl >> 4;
  const int oy_g = (tl >> 2) & 3;
  const int ky_g = tl & 3;
  const int iy   = 2 * oy_g - 1 + ky_g;
  const unsigned rowm = ((unsigned)iy < 8u) ? 0xFFFFFFFFu : 0u;
  const int iyc  = iy < 0 ? 0 : (iy > 7 ? 7 : iy);
  const int swzg = bl_g & 7;
  const int gro0 = (bl_g * 2 + 0) * 64 + ((iyc ^ swzg) << 3);
  const int gro1 = (bl_g * 2 + 1) * 64 + ((iyc ^ swzg) << 3);
  // B-write dsts: ml = bl*16+oy*4+ox, byte col = ncs*32 + ky*8
  char* bwd[2][4];
#pragma unroll
  for (int ncs = 0; ncs < 2; ++ncs)
#pragma unroll
    for (int ox = 0; ox < 4; ++ox) {
      const int ml = bl_g * 16 + oy_g * 4 + ox;
      const int gk = ncs * 2 + (ky_g >> 1);
      bwd[ncs][ox] = BsB + ml * 64 + ((gk ^ ((ml >> 1) & 3)) << 4) + ((ky_g & 1) << 3);
    }

  // -------- fragment read pointers
  const char* afp[4];
#pragma unroll
  for (int zf = 0; zf < 4; ++zf) {
    const int ar = zf * 16 + llo;
    afp[zf] = AsB + ar * 64 + ((lhi ^ ((ar >> 1) & 3)) << 4);
  }
  const char* bfp[4];
#pragma unroll
  for (int mf = 0; mf < 4; ++mf) {
    const int mr = wl * 64 + mf * 16 + llo;
    bfp[mf] = BsB + mr * 64 + ((lhi ^ ((mr >> 1) & 3)) << 4);
  }

  f32x4 acc[4][4] = {};

  // tap selects: row[0..7] = r0.xyzw r1.xyzw; tap(ox,kx) = row[2ox-1+kx]
  uint2 ub[2][4];
  auto gather = [&](const float* rw) {
#pragma unroll
    for (int ncs = 0; ncs < 2; ++ncs) {
      const int gro = ncs ? gro1 : gro0;
      const float4 r0 = *(const float4*)(rw + gro);
      const float4 r1 = *(const float4*)(rw + gro + 4);
      uint2 t;
      t.x = packbf(0.f, r0.x) & rowm;  t.y = packbf(r0.y, r0.z) & rowm;  ub[ncs][0] = t;
      t.x = packbf(r0.y, r0.z) & rowm; t.y = packbf(r0.w, r1.x) & rowm;  ub[ncs][1] = t;
      t.x = packbf(r0.w, r1.x) & rowm; t.y = packbf(r1.y, r1.z) & rowm;  ub[ncs][2] = t;
      t.x = packbf(r1.y, r1.z) & rowm; t.y = packbf(r1.w, 0.f) & rowm;   ub[ncs][3] = t;
    }
  };
  auto writeB = [&]() {
#pragma unroll
    for (int ncs = 0; ncs < 2; ++ncs)
#pragma unroll
      for (int ox = 0; ox < 4; ++ox) *(uint2*)bwd[ncs][ox] = ub[ncs][ox];
  };
  auto domfma = [&]() {
    bf16x8 bfv[4];
#pragma unroll
    for (int mf = 0; mf < 4; ++mf) bfv[mf] = *(const bf16x8*)bfp[mf];
#pragma unroll
    for (int zf = 0; zf < 4; ++zf) {
      const bf16x8 af = *(const bf16x8*)afp[zf];
#pragma unroll
      for (int mf = 0; mf < 4; ++mf)
        acc[zf][mf] = __builtin_amdgcn_mfma_f32_16x16x32_bf16(af, bfv[mf], acc[zf][mf], 0, 0, 0);
    }
  };

  // -------- prologue: prefetch chunks 0,1 of this K-half; stage 0 into raw0
  float4 ra0 = *(const float4*)(gsrc);
  float4 ra1 = *(const float4*)(gsrc + 256);
  float4 rb0 = *(const float4*)(gsrc + 8192);
  float4 rb1 = *(const float4*)(gsrc + 8192 + 256);
  float4 wa0 = *(const float4*)(wsrc);
  float4 wa1 = *(const float4*)(wsrc + 65536);
  float4 wb0 = *(const float4*)(wsrc + 32);
  float4 wb1 = *(const float4*)(wsrc + 65536 + 32);
  *(float4*)rd0a = ra0;
  *(float4*)rd0b = ra1;
  LDS_BARRIER();

  for (int ck = 0; ck < 32; ck += 2) {
    // ============ even chunk ck (gather raw0, stage ck+1 -> raw1) ============
    {
      uint2 a0w, a1w;
      a0w.x = packbf(wa0.x, wa0.y); a0w.y = packbf(wa0.z, wa0.w);
      a1w.x = packbf(wa1.x, wa1.y); a1w.y = packbf(wa1.z, wa1.w);
      if (ck + 2 < 32) {
        ra0 = *(const float4*)(gsrc + (size_t)(ck + 2) * 8192);
        ra1 = *(const float4*)(gsrc + (size_t)(ck + 2) * 8192 + 256);
        wa0 = *(const float4*)(wsrc + (ck + 2) * 32);
        wa1 = *(const float4*)(wsrc + 65536 + (ck + 2) * 32);
      }
      gather(rawB0);
      LDS_BARRIER();               // prev MFMAs + this gather done reading LDS
      *(uint2*)ad0 = a0w;
      *(uint2*)ad1 = a1w;
      writeB();
      *(float4*)rd1a = rb0;        // stage chunk ck+1 (loaded 2 phases ago)
      *(float4*)rd1b = rb1;
      LDS_BARRIER();               // tiles + raw1 visible
      domfma();
    }
    // ============ odd chunk ck+1 (gather raw1, stage ck+2 -> raw0) ===========
    {
      uint2 a0w, a1w;
      a0w.x = packbf(wb0.x, wb0.y); a0w.y = packbf(wb0.z, wb0.w);
      a1w.x = packbf(wb1.x, wb1.y); a1w.y = packbf(wb1.z, wb1.w);
      if (ck + 3 < 32) {
        rb0 = *(const float4*)(gsrc + (size_t)(ck + 3) * 8192);
        rb1 = *(const float4*)(gsrc + (size_t)(ck + 3) * 8192 + 256);
        wb0 = *(const float4*)(wsrc + (ck + 3) * 32);
        wb1 = *(const float4*)(wsrc + 65536 + (ck + 3) * 32);
      }
      gather(rawB1);
      LDS_BARRIER();
      *(uint2*)ad0 = a0w;
      *(uint2*)ad1 = a1w;
      writeB();
      if (ck + 2 < 32) { *(float4*)rd0a = ra0; *(float4*)rd0b = ra1; }
      LDS_BARRIER();
      domfma();
    }
  }

  // -------- combine the two K-halves: kt1 dumps acc, kt0 adds --------------
  __syncthreads();                 // all waves done with tiles
  float* const sc = (float*)lds;   // 64KB scratch, layout [c=0..63][tl=0..255]
  if (kt == 1) {
#pragma unroll
    for (int zf = 0; zf < 4; ++zf)
#pragma unroll
      for (int mf = 0; mf < 4; ++mf)
#pragma unroll
        for (int r = 0; r < 4; ++r)
          sc[(((zf * 4 + mf) << 2) + r) * 256 + tl] = acc[zf][mf][r];
  }
  __syncthreads();
  if (kt == 1) return;             // no further barriers below

#pragma unroll
  for (int zf = 0; zf < 4; ++zf)
#pragma unroll
    for (int mf = 0; mf < 4; ++mf)
#pragma unroll
      for (int r = 0; r < 4; ++r)
        acc[zf][mf][r] += sc[(((zf * 4 + mf) << 2) + r) * 256 + tl];

  // -------- per-channel stats (sum, sumsq) over the wave's 64 m
#pragma unroll
  for (int zf = 0; zf < 4; ++zf) {
    float s[4], ss[4];
#pragma unroll
    for (int r = 0; r < 4; ++r) {
      s[r]  = acc[zf][0][r] + acc[zf][1][r] + acc[zf][2][r] + acc[zf][3][r];
      ss[r] = acc[zf][0][r] * acc[zf][0][r] + acc[zf][1][r] * acc[zf][1][r]
            + acc[zf][2][r] * acc[zf][2][r] + acc[zf][3][r] * acc[zf][3][r];
    }
#pragma unroll
    for (int off = 1; off <= 8; off <<= 1) {
#pragma unroll
      for (int r = 0; r < 4; ++r) {
        s[r]  += __shfl_xor(s[r], off);
        ss[r] += __shfl_xor(ss[r], off);
      }
    }
    if (llo == 0) {
      const int ch = g * 256 + z0 + zf * 16 + lhi * 4;
#pragma unroll
      for (int r = 0; r < 4; ++r) {
        atomicAdd(&stats[2 * (ch + r)],     s[r]);
        atomicAdd(&stats[2 * (ch + r) + 1], ss[r]);
      }
    }
  }

  // -------- store raw conv to d_out in fold layout
#pragma unroll
  for (int zf = 0; zf < 4; ++zf) {
    const int zch = z0 + zf * 16 + lhi * 4;       // + r below
#pragma unroll
    for (int mf = 0; mf < 4; ++mf) {
      const int mm  = m0 + wl * 64 + mf * 16 + llo;
      const int bb  = mm >> 4;
      const int o_y = (mm >> 2) & 3;
      const int o_x = mm & 3;
      float* op = out + (((size_t)bb * 256 + zch) * 32 + hp * 4 + o_y) * 32
                      + wp * 4 + o_x;
#pragma unroll
      for (int r = 0; r < 4; ++r) op[(size_t)r * 1024] = acc[zf][mf][r];
    }
  }
}

// Pass 2: in-place BatchNorm (batch stats) + LeakyReLU on the fold-layout buffer.
__global__ __launch_bounds__(256) void bn_lrelu(
    float* __restrict__ out,
    const float* __restrict__ stats,
    const float* __restrict__ gamma,
    const float* __restrict__ beta)
{
  size_t t = (size_t)blockIdx.x * blockDim.x + threadIdx.x;
  size_t o = t * 4;                    // float4 per thread
  int X0 = (int)(o & 31);
  int Y  = (int)((o >> 5) & 31);
  int z  = (int)((o >> 10) & 255);
  int ch = ((Y >> 2) * 8 + (X0 >> 2)) * 256 + z;  // (hp*8+wp)*256 + z
  float s  = stats[2 * ch];
  float ss = stats[2 * ch + 1];
  float mean = s * (1.f / 512.f);
  float var  = fmaf(-mean, mean, ss * (1.f / 512.f));
  float inv  = gamma[ch] * rsqrtf(var + kEps);
  float sh   = fmaf(-mean, inv, beta[ch]);
  float4 v = *(float4*)&out[o];
  float vv[4] = {v.x, v.y, v.z, v.w};
#pragma unroll
  for (int j = 0; j < 4; ++j) {
    float y = fmaf(vv[j], inv, sh);
    vv[j] = y > 0.f ? y : kLrelu * y;
  }
  *(float4*)&out[o] = make_float4(vv[0], vv[1], vv[2], vv[3]);
}

extern "C" void kernel_launch(void* const* d_in, const int* in_sizes, int n_in,
                              void* d_out, int out_size, void* d_ws, size_t ws_size,
                              hipStream_t stream) {
  const float* input  = (const float*)d_in[0];
  const float* weight = (const float*)d_in[1];
  const float* gamma  = (const float*)d_in[2];
  const float* beta   = (const float*)d_in[3];
  float* out   = (float*)d_out;
  float* stats = (float*)d_ws;  // 16384 * 2 floats = 128 KB

  (void)hipMemsetAsync(stats, 0, (size_t)16384 * 2 * sizeof(float), stream);

  conv_mfma<<<512, 512, 0, stream>>>(input, weight, out, stats);

  int n4 = out_size / 4;               // 2,097,152 float4s
  bn_lrelu<<<(n4 + 255) / 256, 256, 0, stream>>>(out, stats, gamma, beta);
}

// Round 11
// 100.414 us; speedup vs baseline: 1.4997x; 1.4997x over previous
//
#include <hip/hip_runtime.h>

namespace {
constexpr float kLrelu = 0.2f;
constexpr float kEps   = 1e-5f;
}

typedef short bf16x8 __attribute__((ext_vector_type(8)));
typedef float f32x4  __attribute__((ext_vector_type(4)));

// LDS-only barrier: waits local ops, does NOT drain vmcnt -> global prefetch
// loads stay in flight across the barrier.
#define LDS_BARRIER() asm volatile("s_waitcnt lgkmcnt(0)\n\ts_barrier" ::: "memory")

// round-to-nearest-even f32 -> bf16 (inputs are finite)
static __device__ __forceinline__ unsigned f2bf(float x) {
  unsigned u = __float_as_uint(x);
  return (u + 0x7FFFu + ((u >> 16) & 1u)) >> 16;
}
static __device__ __forceinline__ unsigned packbf(float a, float b) {
  return f2bf(a) | (f2bf(b) << 16);
}

// Fully fused: grouped conv (bf16 MFMA) + block-local BatchNorm stats +
// BN apply + LeakyReLU + fold-layout store, ONE kernel, no atomics/grid-sync.
// Block = (g, zt): 64 z-channels x ALL 512 m -> BN stats are block-local.
// 256 blocks x 1024 threads (16 waves, wave tile 64z x 32m). K-loop core is
// the verified R7 structure (swizzles/gather identical, mappings rescaled).
__global__ __launch_bounds__(1024, 1) void conv_bn_fused(
    const float* __restrict__ input,   // [32,128,64,64]
    const float* __restrict__ weight,  // [16384, 2048]  (k = nc*16 + ky*4 + kx)
    float* __restrict__ out,           // [32,256,32,32] FINAL (post BN+LReLU)
    const float* __restrict__ gamma,
    const float* __restrict__ beta)
{
  // raw patch tiles: 64 patches (32 b x 2 nc) x 64 floats, row-XOR swizzle:
  //   addr(fl) = pl*64 + ((py ^ (bl&7))<<3) + px        (16 KB per buffer)
  __shared__ __align__(16) float raw0[64 * 64];
  __shared__ __align__(16) float raw1[64 * 64];
  // GEMM tiles, row = 64B (32 bf16), 16B-granule XOR swizzle (gk ^ ((row>>1)&3))
  __shared__ __align__(16) char Bs[512 * 64];     // 32 KB
  __shared__ __align__(16) char As[64 * 64];      // 4 KB

  const int bid  = blockIdx.x;
  const int orig = (bid & 7) * 32 + (bid >> 3);   // XCD-chunked (256 % 8 == 0)
  const int g    = orig >> 2;                     // group 0..63
  const int zt   = orig & 3;                      // z tile 0..3
  const int hp = g >> 3, wp = g & 7;
  const int z0 = zt * 64;

  const int tid  = threadIdx.x;
  const int lane = tid & 63;
  const int w    = tid >> 6;                      // wave 0..15, m-range = w*32
  const int llo  = lane & 15, lhi = lane >> 4;

  // -------- raw staging: one float4/thread/chunk (64 patches x 16 float4)
  const int pl_s  = tid >> 4;                     // patch 0..63
  const int f4    = tid & 15;
  const int bl_s  = pl_s >> 1;                    // b 0..31
  const int ncs_s = pl_s & 1;
  const int py_s  = f4 >> 1, h_s = f4 & 1;
  const float* const gsrc = input
      + ((size_t)bl_s * 128 + ncs_s) * 4096
      + (hp * 8 + py_s) * 64 + wp * 8 + (h_s << 2);   // + ck*8192 per chunk
  const int roff = pl_s * 64 + ((py_s ^ (bl_s & 7)) << 3) + (h_s << 2);
  float* const rd0 = raw0 + roff;
  float* const rd1 = raw1 + roff;

  // -------- weight staging (threads < 512): az0=tid>>3 (0..63), kq=tid&7
  const int az0 = tid >> 3;
  const int kq  = tid & 7;
  const float* const wsrc =
      weight + ((size_t)(g * 256 + z0 + (az0 & 63))) * 2048 + kq * 4;
  const int aswz = (az0 >> 1) & 3;
  char* const ad0 = As + (az0 & 63) * 64 + (((kq >> 1) ^ aswz) << 4) + ((kq & 1) << 3);

  // -------- row-gather: thread -> (ncs=tid>>9, bl, oy, ky); one task/thread
  const int rr   = tid & 511;
  const int bl_g = rr >> 4;                       // 0..31
  const int oy_g = (rr >> 2) & 3;
  const int ky_g = rr & 3;
  const int ncs  = tid >> 9;
  const int iy   = 2 * oy_g - 1 + ky_g;
  const unsigned rowm = ((unsigned)iy < 8u) ? 0xFFFFFFFFu : 0u;
  const int iyc  = iy < 0 ? 0 : (iy > 7 ? 7 : iy);
  const int swzg = bl_g & 7;
  const int gro  = (bl_g * 2 + ncs) * 64 + ((iyc ^ swzg) << 3);
  // B-write dsts: ml = bl*16+oy*4+ox, byte col = ncs*32 + ky*8
  char* bwd[4];
#pragma unroll
  for (int ox = 0; ox < 4; ++ox) {
    const int ml = bl_g * 16 + oy_g * 4 + ox;
    const int gk = ncs * 2 + (ky_g >> 1);
    bwd[ox] = Bs + ml * 64 + ((gk ^ ((ml >> 1) & 3)) << 4) + ((ky_g & 1) << 3);
  }

  // -------- fragment read pointers
  const char* afp[4];
#pragma unroll
  for (int zf = 0; zf < 4; ++zf) {
    const int ar = zf * 16 + llo;
    afp[zf] = As + ar * 64 + ((lhi ^ ((ar >> 1) & 3)) << 4);
  }
  const char* bfp[2];
#pragma unroll
  for (int mf = 0; mf < 2; ++mf) {
    const int mr = w * 32 + mf * 16 + llo;        // 0..511
    bfp[mf] = Bs + mr * 64 + ((lhi ^ ((mr >> 1) & 3)) << 4);
  }

  f32x4 acc[4][2] = {};

  // tap selects: row[0..7] = r0.xyzw r1.xyzw; tap(ox,kx) = row[2ox-1+kx]
  uint2 ub[4];
  auto gather = [&](const float* rw) {
    const float4 r0 = *(const float4*)(rw + gro);
    const float4 r1 = *(const float4*)(rw + gro + 4);
    uint2 t;
    t.x = packbf(0.f, r0.x) & rowm;  t.y = packbf(r0.y, r0.z) & rowm;  ub[0] = t;
    t.x = packbf(r0.y, r0.z) & rowm; t.y = packbf(r0.w, r1.x) & rowm;  ub[1] = t;
    t.x = packbf(r0.w, r1.x) & rowm; t.y = packbf(r1.y, r1.z) & rowm;  ub[2] = t;
    t.x = packbf(r1.y, r1.z) & rowm; t.y = packbf(r1.w, 0.f) & rowm;   ub[3] = t;
  };
  auto writeB = [&]() {
#pragma unroll
    for (int ox = 0; ox < 4; ++ox) *(uint2*)bwd[ox] = ub[ox];
  };
  auto domfma = [&]() {
    bf16x8 bfv[2];
#pragma unroll
    for (int mf = 0; mf < 2; ++mf) bfv[mf] = *(const bf16x8*)bfp[mf];
#pragma unroll
    for (int zf = 0; zf < 4; ++zf) {
      const bf16x8 af = *(const bf16x8*)afp[zf];
#pragma unroll
      for (int mf = 0; mf < 2; ++mf)
        acc[zf][mf] = __builtin_amdgcn_mfma_f32_16x16x32_bf16(af, bfv[mf], acc[zf][mf], 0, 0, 0);
    }
  };

  // -------- prologue: prefetch chunks 0,1; stage chunk 0 into raw0
  const bool doA = (tid < 512);
  float4 ra = *(const float4*)(gsrc);
  float4 rb = *(const float4*)(gsrc + 8192);
  float4 wa, wb;
  if (doA) {
    wa = *(const float4*)(wsrc);
    wb = *(const float4*)(wsrc + 32);
  }
  *(float4*)rd0 = ra;
  LDS_BARRIER();

  for (int ck = 0; ck < 64; ck += 2) {
    // ============ even chunk ck (gather raw0, stage ck+1 -> raw1) ============
    {
      uint2 a0w;
      if (doA) { a0w.x = packbf(wa.x, wa.y); a0w.y = packbf(wa.z, wa.w); }
      if (ck + 2 < 64) {
        ra = *(const float4*)(gsrc + (size_t)(ck + 2) * 8192);
        if (doA) wa = *(const float4*)(wsrc + (ck + 2) * 32);
      }
      gather(raw0);
      LDS_BARRIER();               // prev MFMAs + this gather done reading LDS
      if (doA) *(uint2*)ad0 = a0w;
      writeB();
      *(float4*)rd1 = rb;          // stage chunk ck+1 (loaded 2 phases ago)
      LDS_BARRIER();               // tiles + raw1 visible
      domfma();
    }
    // ============ odd chunk ck+1 (gather raw1, stage ck+2 -> raw0) ===========
    {
      uint2 a0w;
      if (doA) { a0w.x = packbf(wb.x, wb.y); a0w.y = packbf(wb.z, wb.w); }
      if (ck + 3 < 64) {
        rb = *(const float4*)(gsrc + (size_t)(ck + 3) * 8192);
        if (doA) wb = *(const float4*)(wsrc + (ck + 3) * 32);
      }
      gather(raw1);
      LDS_BARRIER();
      if (doA) *(uint2*)ad0 = a0w;
      writeB();
      if (ck + 2 < 64) *(float4*)rd0 = ra;   // stage chunk ck+2
      LDS_BARRIER();
      domfma();
    }
  }

  // ================= block-local BN: stats -> inv/shift -> apply =============
  __syncthreads();                 // all waves done with tiles; reuse raw0/raw1
  float* const sums  = (float*)raw0;        // [ch_local 0..63][wave 0..15]
  float* const sums2 = sums + 1024;
#pragma unroll
  for (int zf = 0; zf < 4; ++zf) {
    float s[4], ss[4];
#pragma unroll
    for (int r = 0; r < 4; ++r) {
      s[r]  = acc[zf][0][r] + acc[zf][1][r];
      ss[r] = acc[zf][0][r] * acc[zf][0][r] + acc[zf][1][r] * acc[zf][1][r];
    }
#pragma unroll
    for (int off = 1; off <= 8; off <<= 1) {
#pragma unroll
      for (int r = 0; r < 4; ++r) {
        s[r]  += __shfl_xor(s[r], off);
        ss[r] += __shfl_xor(ss[r], off);
      }
    }
    if (llo == 0) {
#pragma unroll
      for (int r = 0; r < 4; ++r) {
        const int chl = zf * 16 + lhi * 4 + r;
        sums[chl * 16 + w]  = s[r];
        sums2[chl * 16 + w] = ss[r];
      }
    }
  }
  __syncthreads();
  float* const invL = (float*)raw1;         // [64]
  float* const shL  = invL + 64;            // [64]
  if (tid < 64) {
    float sum = 0.f, sq = 0.f;
#pragma unroll
    for (int i = 0; i < 16; ++i) { sum += sums[tid * 16 + i]; sq += sums2[tid * 16 + i]; }
    const int ch = g * 256 + z0 + tid;
    const float mean = sum * (1.f / 512.f);
    const float var  = fmaf(-mean, mean, sq * (1.f / 512.f));
    const float iv   = gamma[ch] * rsqrtf(var + kEps);
    invL[tid] = iv;
    shL[tid]  = fmaf(-mean, iv, beta[ch]);
  }
  __syncthreads();

  // -------- apply BN + LeakyReLU in registers; store FINAL to fold layout
#pragma unroll
  for (int zf = 0; zf < 4; ++zf) {
    float iv[4], sh[4];
#pragma unroll
    for (int r = 0; r < 4; ++r) {
      const int chl = zf * 16 + lhi * 4 + r;
      iv[r] = invL[chl];
      sh[r] = shL[chl];
    }
    const int zch = z0 + zf * 16 + lhi * 4;       // + r below
#pragma unroll
    for (int mf = 0; mf < 2; ++mf) {
      const int mm  = w * 32 + mf * 16 + llo;     // 0..511
      const int bb  = mm >> 4;
      const int o_y = (mm >> 2) & 3;
      const int o_x = mm & 3;
      float* op = out + (((size_t)bb * 256 + zch) * 32 + hp * 4 + o_y) * 32
                      + wp * 4 + o_x;
#pragma unroll
      for (int r = 0; r < 4; ++r) {
        float y = fmaf(acc[zf][mf][r], iv[r], sh[r]);
        y = y > 0.f ? y : kLrelu * y;
        op[(size_t)r * 1024] = y;
      }
    }
  }
}

extern "C" void kernel_launch(void* const* d_in, const int* in_sizes, int n_in,
                              void* d_out, int out_size, void* d_ws, size_t ws_size,
                              hipStream_t stream) {
  const float* input  = (const float*)d_in[0];
  const float* weight = (const float*)d_in[1];
  const float* gamma  = (const float*)d_in[2];
  const float* beta   = (const float*)d_in[3];
  float* out = (float*)d_out;

  conv_bn_fused<<<256, 1024, 0, stream>>>(input, weight, out, gamma, beta);
}

// Round 12
// 89.534 us; speedup vs baseline: 1.6819x; 1.1215x over previous
//
#include <hip/hip_runtime.h>

namespace {
constexpr float kLrelu = 0.2f;
constexpr float kEps   = 1e-5f;
}

typedef short bf16x8 __attribute__((ext_vector_type(8)));
typedef float f32x4  __attribute__((ext_vector_type(4)));

// LDS-only barrier: waits local ops, does NOT drain vmcnt -> global prefetch
// loads stay in flight across the barrier.
#define LDS_BARRIER() asm volatile("s_waitcnt lgkmcnt(0)\n\ts_barrier" ::: "memory")

// round-to-nearest-even f32 -> bf16 (inputs are finite)
static __device__ __forceinline__ unsigned f2bf(float x) {
  unsigned u = __float_as_uint(x);
  return (u + 0x7FFFu + ((u >> 16) & 1u)) >> 16;
}
static __device__ __forceinline__ unsigned packbf(float a, float b) {
  return f2bf(a) | (f2bf(b) << 16);
}

// Fully fused: grouped conv (bf16 MFMA) + block-local BatchNorm + LeakyReLU +
// fold-layout store. Block = (g, zt): 64 z-channels x ALL 512 m (BN local).
// 256 blocks x 512 threads = 8 waves, wave tile 64z x 64m (R5/R7-verified core:
// 16 MFMA : 8 frag reads per wave). 2 blocks/CU (LDS 68KB) -> two independent
// barrier domains; half the A-fragment read redundancy of the 16-wave shape.
__global__ __launch_bounds__(512, 4) void conv_bn_fused(
    const float* __restrict__ input,   // [32,128,64,64]
    const float* __restrict__ weight,  // [16384, 2048]  (k = nc*16 + ky*4 + kx)
    float* __restrict__ out,           // [32,256,32,32] FINAL (post BN+LReLU)
    const float* __restrict__ gamma,
    const float* __restrict__ beta)
{
  // raw patch tiles: 64 patches (32 b x 2 nc) x 64 floats, row-XOR swizzle:
  //   addr(fl) = pl*64 + ((py ^ (bl&7))<<3) + px        (16 KB per buffer)
  __shared__ __align__(16) float raw0[64 * 64];
  __shared__ __align__(16) float raw1[64 * 64];
  // GEMM tiles, row = 64B (32 bf16), 16B-granule XOR swizzle (gk ^ ((row>>1)&3))
  __shared__ __align__(16) char Bs[512 * 64];     // 32 KB
  __shared__ __align__(16) char As[64 * 64];      // 4 KB

  const int bid  = blockIdx.x;
  const int orig = (bid & 7) * 32 + (bid >> 3);   // XCD-chunked (256 % 8 == 0)
  const int g    = orig >> 2;                     // group 0..63
  const int zt   = orig & 3;                      // z tile 0..3
  const int hp = g >> 3, wp = g & 7;
  const int z0 = zt * 64;

  const int tid  = threadIdx.x;
  const int lane = tid & 63;
  const int w    = tid >> 6;                      // wave 0..7, m-range = w*64
  const int llo  = lane & 15, lhi = lane >> 4;

  // -------- raw staging: two float4/thread/chunk (64 patches x 16 float4)
  const int pl_s  = tid >> 3;                     // patch 0..63
  const int f4    = tid & 7;
  const int bl_s  = pl_s >> 1;                    // b 0..31
  const int ncs_s = pl_s & 1;
  const int py_s  = f4 >> 1, h_s = f4 & 1;
  const float* const gsrc = input
      + ((size_t)bl_s * 128 + ncs_s) * 4096
      + (hp * 8 + py_s) * 64 + wp * 8 + (h_s << 2);   // 2nd load: +256 (py+4)
  const int roffA = pl_s * 64 + ((py_s ^ (bl_s & 7)) << 3) + (h_s << 2);
  const int roffB = pl_s * 64 + (((py_s + 4) ^ (bl_s & 7)) << 3) + (h_s << 2);
  float* const rd0a = raw0 + roffA;  float* const rd0b = raw0 + roffB;
  float* const rd1a = raw1 + roffA;  float* const rd1b = raw1 + roffB;

  // -------- weight staging: one task/thread: az0=tid>>3 (0..63), kq=tid&7
  const int az0 = tid >> 3;
  const int kq  = tid & 7;
  const float* const wsrc =
      weight + ((size_t)(g * 256 + z0 + az0)) * 2048 + kq * 4;
  const int aswz = (az0 >> 1) & 3;
  char* const ad0 = As + az0 * 64 + (((kq >> 1) ^ aswz) << 4) + ((kq & 1) << 3);

  // -------- row-gather: 2 tasks/thread (ncs=0,1): bl=tid>>4, oy, ky
  const int bl_g = tid >> 4;                      // 0..31
  const int oy_g = (tid >> 2) & 3;
  const int ky_g = tid & 3;
  const int iy   = 2 * oy_g - 1 + ky_g;
  const unsigned rowm = ((unsigned)iy < 8u) ? 0xFFFFFFFFu : 0u;
  const int iyc  = iy < 0 ? 0 : (iy > 7 ? 7 : iy);
  const int swzg = bl_g & 7;
  const int gro0 = (bl_g * 2 + 0) * 64 + ((iyc ^ swzg) << 3);
  const int gro1 = (bl_g * 2 + 1) * 64 + ((iyc ^ swzg) << 3);
  // B-write dsts: ml = bl*16+oy*4+ox, byte col = ncs*32 + ky*8
  char* bwd[2][4];
#pragma unroll
  for (int ncs = 0; ncs < 2; ++ncs)
#pragma unroll
    for (int ox = 0; ox < 4; ++ox) {
      const int ml = bl_g * 16 + oy_g * 4 + ox;
      const int gk = ncs * 2 + (ky_g >> 1);
      bwd[ncs][ox] = Bs + ml * 64 + ((gk ^ ((ml >> 1) & 3)) << 4) + ((ky_g & 1) << 3);
    }

  // -------- fragment read pointers
  const char* afp[4];
#pragma unroll
  for (int zf = 0; zf < 4; ++zf) {
    const int ar = zf * 16 + llo;
    afp[zf] = As + ar * 64 + ((lhi ^ ((ar >> 1) & 3)) << 4);
  }
  const char* bfp[4];
#pragma unroll
  for (int mf = 0; mf < 4; ++mf) {
    const int mr = w * 64 + mf * 16 + llo;        // 0..511
    bfp[mf] = Bs + mr * 64 + ((lhi ^ ((mr >> 1) & 3)) << 4);
  }

  f32x4 acc[4][4] = {};

  // tap selects: row[0..7] = r0.xyzw r1.xyzw; tap(ox,kx) = row[2ox-1+kx]
  uint2 ub[2][4];
  auto gather = [&](const float* rw) {
#pragma unroll
    for (int ncs = 0; ncs < 2; ++ncs) {
      const int gro = ncs ? gro1 : gro0;
      const float4 r0 = *(const float4*)(rw + gro);
      const float4 r1 = *(const float4*)(rw + gro + 4);
      uint2 t;
      t.x = packbf(0.f, r0.x) & rowm;  t.y = packbf(r0.y, r0.z) & rowm;  ub[ncs][0] = t;
      t.x = packbf(r0.y, r0.z) & rowm; t.y = packbf(r0.w, r1.x) & rowm;  ub[ncs][1] = t;
      t.x = packbf(r0.w, r1.x) & rowm; t.y = packbf(r1.y, r1.z) & rowm;  ub[ncs][2] = t;
      t.x = packbf(r1.y, r1.z) & rowm; t.y = packbf(r1.w, 0.f) & rowm;   ub[ncs][3] = t;
    }
  };
  auto writeB = [&]() {
#pragma unroll
    for (int ncs = 0; ncs < 2; ++ncs)
#pragma unroll
      for (int ox = 0; ox < 4; ++ox) *(uint2*)bwd[ncs][ox] = ub[ncs][ox];
  };
  auto domfma = [&]() {
    bf16x8 bfv[4];
#pragma unroll
    for (int mf = 0; mf < 4; ++mf) bfv[mf] = *(const bf16x8*)bfp[mf];
#pragma unroll
    for (int zf = 0; zf < 4; ++zf) {
      const bf16x8 af = *(const bf16x8*)afp[zf];
#pragma unroll
      for (int mf = 0; mf < 4; ++mf)
        acc[zf][mf] = __builtin_amdgcn_mfma_f32_16x16x32_bf16(af, bfv[mf], acc[zf][mf], 0, 0, 0);
    }
  };

  // -------- prologue: prefetch chunks 0,1; stage chunk 0 into raw0
  float4 ra0 = *(const float4*)(gsrc);
  float4 ra1 = *(const float4*)(gsrc + 256);
  float4 rb0 = *(const float4*)(gsrc + 8192);
  float4 rb1 = *(const float4*)(gsrc + 8192 + 256);
  float4 wa  = *(const float4*)(wsrc);
  float4 wb  = *(const float4*)(wsrc + 32);
  *(float4*)rd0a = ra0;
  *(float4*)rd0b = ra1;
  LDS_BARRIER();

  for (int ck = 0; ck < 64; ck += 2) {
    // ============ even chunk ck (gather raw0, stage ck+1 -> raw1) ============
    {
      uint2 a0w;
      a0w.x = packbf(wa.x, wa.y); a0w.y = packbf(wa.z, wa.w);
      if (ck + 2 < 64) {
        ra0 = *(const float4*)(gsrc + (size_t)(ck + 2) * 8192);
        ra1 = *(const float4*)(gsrc + (size_t)(ck + 2) * 8192 + 256);
        wa  = *(const float4*)(wsrc + (ck + 2) * 32);
      }
      gather(raw0);
      LDS_BARRIER();               // prev MFMAs + this gather done reading LDS
      *(uint2*)ad0 = a0w;
      writeB();
      *(float4*)rd1a = rb0;        // stage chunk ck+1 (loaded 2 phases ago)
      *(float4*)rd1b = rb1;
      LDS_BARRIER();               // tiles + raw1 visible
      domfma();
    }
    // ============ odd chunk ck+1 (gather raw1, stage ck+2 -> raw0) ===========
    {
      uint2 a0w;
      a0w.x = packbf(wb.x, wb.y); a0w.y = packbf(wb.z, wb.w);
      if (ck + 3 < 64) {
        rb0 = *(const float4*)(gsrc + (size_t)(ck + 3) * 8192);
        rb1 = *(const float4*)(gsrc + (size_t)(ck + 3) * 8192 + 256);
        wb  = *(const float4*)(wsrc + (ck + 3) * 32);
      }
      gather(raw1);
      LDS_BARRIER();
      *(uint2*)ad0 = a0w;
      writeB();
      if (ck + 2 < 64) { *(float4*)rd0a = ra0; *(float4*)rd0b = ra1; }
      LDS_BARRIER();
      domfma();
    }
  }

  // ================= block-local BN: stats -> inv/shift -> apply =============
  __syncthreads();                 // all waves done with tiles; reuse raw0/raw1
  float* const sums  = (float*)raw0;        // [ch_local 0..63][wave 0..7]
  float* const sums2 = sums + 512;
#pragma unroll
  for (int zf = 0; zf < 4; ++zf) {
    float s[4], ss[4];
#pragma unroll
    for (int r = 0; r < 4; ++r) {
      s[r]  = acc[zf][0][r] + acc[zf][1][r] + acc[zf][2][r] + acc[zf][3][r];
      ss[r] = acc[zf][0][r] * acc[zf][0][r] + acc[zf][1][r] * acc[zf][1][r]
            + acc[zf][2][r] * acc[zf][2][r] + acc[zf][3][r] * acc[zf][3][r];
    }
#pragma unroll
    for (int off = 1; off <= 8; off <<= 1) {
#pragma unroll
      for (int r = 0; r < 4; ++r) {
        s[r]  += __shfl_xor(s[r], off);
        ss[r] += __shfl_xor(ss[r], off);
      }
    }
    if (llo == 0) {
#pragma unroll
      for (int r = 0; r < 4; ++r) {
        const int chl = zf * 16 + lhi * 4 + r;
        sums[chl * 8 + w]  = s[r];
        sums2[chl * 8 + w] = ss[r];
      }
    }
  }
  __syncthreads();
  float* const invL = (float*)raw1;         // [64]
  float* const shL  = invL + 64;            // [64]
  if (tid < 64) {
    float sum = 0.f, sq = 0.f;
#pragma unroll
    for (int i = 0; i < 8; ++i) { sum += sums[tid * 8 + i]; sq += sums2[tid * 8 + i]; }
    const int ch = g * 256 + z0 + tid;
    const float mean = sum * (1.f / 512.f);
    const float var  = fmaf(-mean, mean, sq * (1.f / 512.f));
    const float iv   = gamma[ch] * rsqrtf(var + kEps);
    invL[tid] = iv;
    shL[tid]  = fmaf(-mean, iv, beta[ch]);
  }
  __syncthreads();

  // -------- apply BN + LeakyReLU in registers; store FINAL to fold layout
#pragma unroll
  for (int zf = 0; zf < 4; ++zf) {
    float iv[4], sh[4];
#pragma unroll
    for (int r = 0; r < 4; ++r) {
      const int chl = zf * 16 + lhi * 4 + r;
      iv[r] = invL[chl];
      sh[r] = shL[chl];
    }
    const int zch = z0 + zf * 16 + lhi * 4;       // + r below
#pragma unroll
    for (int mf = 0; mf < 4; ++mf) {
      const int mm  = w * 64 + mf * 16 + llo;     // 0..511
      const int bb  = mm >> 4;
      const int o_y = (mm >> 2) & 3;
      const int o_x = mm & 3;
      float* op = out + (((size_t)bb * 256 + zch) * 32 + hp * 4 + o_y) * 32
                      + wp * 4 + o_x;
#pragma unroll
      for (int r = 0; r < 4; ++r) {
        float y = fmaf(acc[zf][mf][r], iv[r], sh[r]);
        y = y > 0.f ? y : kLrelu * y;
        op[(size_t)r * 1024] = y;
      }
    }
  }
}

extern "C" void kernel_launch(void* const* d_in, const int* in_sizes, int n_in,
                              void* d_out, int out_size, void* d_ws, size_t ws_size,
                              hipStream_t stream) {
  const float* input  = (const float*)d_in[0];
  const float* weight = (const float*)d_in[1];
  const float* gamma  = (const float*)d_in[2];
  const float* beta   = (const float*)d_in[3];
  float* out = (float*)d_out;

  conv_bn_fused<<<256, 512, 0, stream>>>(input, weight, out, gamma, beta);
}